// Round 21
// baseline (57.820 us; speedup 1.0000x reference)
//
#include <hip/hip_runtime.h>
#include <hip/hip_bf16.h>
#include <math.h>

// DiscriminationLoss via MFMA (R21):
//   S[k,c] = sum_{p: label[p]=k} pred[c,p],  N[k] = |{p: label[p]=k}|, k=1..32
//   A[k]   = N[k] * sum_c S[k,c]^2
//   L      = sum_{i<j} log(max(3 - sqrt(A_i + A_j), 0)^2 + 1);  out = L*(K-1)/K
//
// Falsification ledger (seg plateau 41.6-41.9us across R14-R20): pipeline
// depth, occupancy 8/16/20w, LDS traffic, bank conflicts, block-sharing,
// sweep order, granule up/down. R21 changes ONLY the tail: fence-free
// grouped atomic publish (ws[row][32], grp=blockIdx&31, NO threadfence --
// R11's cost was the per-block buffer_wbl2, not the atomics; ordering comes
// from the graph edge) + memset(36KB) + finish. reduce1 node and 1.18MB
// slab round-trip deleted. seg main loop byte-identical to R14 (41.6 best).

typedef __attribute__((ext_vector_type(8))) short short8;
typedef __attribute__((ext_vector_type(4))) float f32x4;

constexpr int NSEGF = 32;            // segments 1..32 (label 0 = background)
constexpr int RPS   = 9;             // 8 channels + count
constexpr int NROWS = NSEGF * RPS;   // 288
constexpr int BLK   = 256;
constexpr int WPB   = 4;
constexpr int NBLK  = 1024;          // 4 blocks/CU co-resident
constexpr int NWAVES= NBLK * WPB;    // 4096 waves
constexpr int TPX   = 128;           // pixels per tile (per wave per buffer)
constexpr int NGRP  = 32;            // atomic contender groups per row
// ws layout: [0, NROWS*NGRP) = accumulation grid [row][grp], memset each call.

#define SCHED_FENCE asm volatile("" ::: "memory")
#define WAITVM(n)   asm volatile("s_waitcnt vmcnt(" #n ")" ::: "memory")

typedef __attribute__((address_space(1))) void A1v;
typedef __attribute__((address_space(3))) void A3v;

__device__ __forceinline__ void gload16(const void* g, void* l) {
  // 16B/lane direct global->LDS DMA; LDS dest = uniform base + lane*16.
  __builtin_amdgcn_global_load_lds((const A1v*)g, (A3v*)l, 16, 0, 0);
}

__device__ __forceinline__ short f2bf(float f) {
  return (short)__bfloat16_as_ushort(__float2bfloat16(f));
}

__device__ __forceinline__ float wave_sum64(float x) {
  int t;
  t = __builtin_amdgcn_update_dpp(0, __float_as_int(x), 0x111, 0xf, 0xf, true); x += __int_as_float(t);
  t = __builtin_amdgcn_update_dpp(0, __float_as_int(x), 0x112, 0xf, 0xf, true); x += __int_as_float(t);
  t = __builtin_amdgcn_update_dpp(0, __float_as_int(x), 0x114, 0xf, 0xf, true); x += __int_as_float(t);
  t = __builtin_amdgcn_update_dpp(0, __float_as_int(x), 0x118, 0xf, 0xf, true); x += __int_as_float(t);
  t = __builtin_amdgcn_update_dpp(0, __float_as_int(x), 0x142, 0xf, 0xf, true); x += __int_as_float(t);
  t = __builtin_amdgcn_update_dpp(0, __float_as_int(x), 0x143, 0xf, 0xf, true); x += __int_as_float(t);
  return x;  // lane 63 holds the sum
}

// Stage one 128-px tile: 4 pred DMA (each covers 2 channel rows of 512B)
// + 1 label DMA (32 lanes). Global source pre-swizzled byte^((c&7)<<4).
__device__ __forceinline__ void stage_tile(const float* __restrict__ pred,
                                           const int*   __restrict__ lab,
                                           float* predbuf, int* labbuf,
                                           size_t px0, int lane, size_t P) {
#pragma unroll
  for (int i = 0; i < 4; ++i) {
    const int c   = 2 * i + (lane >> 5);
    const int swb = (((lane & 31) * 16) ^ ((c & 7) << 4));  // byte within 512B row
    gload16(pred + (size_t)c * P + px0 + (swb >> 2), predbuf + i * 256);
  }
  if (lane < 32) gload16(lab + px0 + lane * 4, labbuf);
}

// Compute one tile (4 steps x 2 MFMA) from this wave's LDS buffer.
__device__ __forceinline__ void compute_tile(const float* __restrict__ pbuf,
                                             const int*   __restrict__ lbuf,
                                             int colq, int quad, int ms0, int ms1,
                                             short8 Bconst,
                                             f32x4& acc0, f32x4& acc1) {
  const short ONE = (short)0x3F80;
  const int  c    = colq & 7;            // lanes 8..15 alias c of colq-8 (broadcast)
  const bool isch = (colq < 8);
  const char* prow = (const char*)(pbuf + c * TPX);
  const int*  lb   = lbuf + quad * 8;
#pragma unroll
  for (int s = 0; s < 4; ++s) {
    const int4 la = *(const int4*)(lb + s * 32);
    const int4 lc = *(const int4*)(lb + s * 32 + 4);
    const int  b0 = (s * 128 + quad * 32) ^ ((c & 7) << 4);   // swizzled byte
    const float4 x = *(const float4*)(prow + b0);
    const float4 y = *(const float4*)(prow + (b0 ^ 16));
    short8 A0, A1, B;
    A0[0] = (la.x == ms0) ? ONE : (short)0;
    A0[1] = (la.y == ms0) ? ONE : (short)0;
    A0[2] = (la.z == ms0) ? ONE : (short)0;
    A0[3] = (la.w == ms0) ? ONE : (short)0;
    A0[4] = (lc.x == ms0) ? ONE : (short)0;
    A0[5] = (lc.y == ms0) ? ONE : (short)0;
    A0[6] = (lc.z == ms0) ? ONE : (short)0;
    A0[7] = (lc.w == ms0) ? ONE : (short)0;
    A1[0] = (la.x == ms1) ? ONE : (short)0;
    A1[1] = (la.y == ms1) ? ONE : (short)0;
    A1[2] = (la.z == ms1) ? ONE : (short)0;
    A1[3] = (la.w == ms1) ? ONE : (short)0;
    A1[4] = (lc.x == ms1) ? ONE : (short)0;
    A1[5] = (lc.y == ms1) ? ONE : (short)0;
    A1[6] = (lc.z == ms1) ? ONE : (short)0;
    A1[7] = (lc.w == ms1) ? ONE : (short)0;
    if (isch) {
      B[0] = f2bf(x.x); B[1] = f2bf(x.y); B[2] = f2bf(x.z); B[3] = f2bf(x.w);
      B[4] = f2bf(y.x); B[5] = f2bf(y.y); B[6] = f2bf(y.z); B[7] = f2bf(y.w);
    } else {
      B = Bconst;
    }
    acc0 = __builtin_amdgcn_mfma_f32_16x16x32_bf16(A0, B, acc0, 0, 0, 0);
    acc1 = __builtin_amdgcn_mfma_f32_16x16x32_bf16(A1, B, acc1, 0, 0, 0);
  }
}

__global__ __launch_bounds__(BLK, 4)
void seg_mfma(const float* __restrict__ pred,
              const int*   __restrict__ lab,
              float*       __restrict__ ws,
              int P) {
  __shared__ __align__(16) float predL[WPB][2][8 * TPX];  // 32 KB (red overlaid)
  __shared__ __align__(16) int   labL[WPB][2][TPX];       // 4 KB

  const int tid  = threadIdx.x;
  const int wid  = tid >> 6;
  const int lane = tid & 63;
  const int colq = lane & 15;   // D col: 0..7 channel, 8 count, 9..15 unused
  const int quad = lane >> 4;   // k-group (8 px each)
  const int ms0  = colq + 1;    // acc0: segments 1..16
  const int ms1  = colq + 17;   // acc1: segments 17..32

  // XCD-bijective block swizzle (1024 % 8 == 0).
  const int bs = (blockIdx.x & 7) * (NBLK / 8) + (blockIdx.x >> 3);
  const int gw = bs * WPB + wid;

  const int spt = (P / TPX) / NWAVES;       // tiles per wave (guarded >= 2)
  const size_t px00 = (size_t)gw * spt * TPX;

  f32x4 acc0 = {0.f, 0.f, 0.f, 0.f};
  f32x4 acc1 = {0.f, 0.f, 0.f, 0.f};

  short8 Bconst;   // col 8 -> bf16 1.0 (counts); cols 9..15 -> 0
  {
    const short v = (colq == 8) ? (short)0x3F80 : (short)0;
#pragma unroll
    for (int i = 0; i < 8; ++i) Bconst[i] = v;
  }

  float* pb0 = &predL[wid][0][0];
  float* pb1 = &predL[wid][1][0];
  int*   lb0 = &labL[wid][0][0];
  int*   lb1 = &labL[wid][1][0];

  // Prologue: stage tiles 0 and 1 (10 DMAs in flight).
  stage_tile(pred, lab, pb0, lb0, px00, lane, (size_t)P);
  stage_tile(pred, lab, pb1, lb1, px00 + TPX, lane, (size_t)P);

  for (int t = 0; t < spt; ++t) {
    // Steady: WAITVM(5) retires tile t's 5 DMAs, leaves tile t+1 in flight.
    if (t < spt - 1) { WAITVM(5); } else { WAITVM(0); }
    const float* pb = (t & 1) ? pb1 : pb0;
    const int*   lb = (t & 1) ? lb1 : lb0;
    compute_tile(pb, lb, colq, quad, ms0, ms1, Bconst, acc0, acc1);
    SCHED_FENCE;   // pin ds_read issue before re-staging this buffer
    if (t + 2 < spt) {
      stage_tile(pred, lab, (t & 1) ? pb1 : pb0, (t & 1) ? lb1 : lb0,
                 px00 + (size_t)(t + 2) * TPX, lane, (size_t)P);
    }
  }

  // Per-wave partials overlaid on this wave's OWN predL (loop done; buffers
  // are wave-private). D layout (m89/m91-verified): col=lane&15,
  // row=(lane>>4)*4+reg. acc0 row r -> seg r+1; acc1 row r -> seg r+17.
  float* redw = &predL[wid][0][0];
  SCHED_FENCE;
  if (colq < RPS) {
#pragma unroll
    for (int r = 0; r < 4; ++r)
      redw[(quad * 4 + r) * RPS + colq] = acc0[r];
#pragma unroll
    for (int r = 0; r < 4; ++r)
      redw[(16 + quad * 4 + r) * RPS + colq] = acc1[r];
  }
  __syncthreads();
  // Fence-free grouped atomic publish: 32 contenders per address, 288
  // independent lines. Ordering vs finish comes from the graph edge.
  const int grp = blockIdx.x & (NGRP - 1);
  for (int v = tid; v < NROWS; v += BLK) {
    float s = 0.f;
#pragma unroll
    for (int w = 0; w < WPB; ++w) s += predL[w][0][v];
    unsafeAtomicAdd(&ws[v * NGRP + grp], s);
  }
}

// Fallback (C != 8 or bad divisibility): LDS-atomic bins, same atomic publish.
__global__ __launch_bounds__(BLK)
void seg_gen(const float* __restrict__ pred,
             const int*   __restrict__ lab,
             float*       __restrict__ ws,
             int P, int C) {
  __shared__ float bins[(NSEGF + 1) * RPS];
  const int tid = threadIdx.x;
  for (int i = tid; i < (NSEGF + 1) * RPS; i += BLK) bins[i] = 0.f;
  __syncthreads();
  const int stride = gridDim.x * BLK;
  const int Cc = C < 8 ? C : 8;
  for (int p = blockIdx.x * BLK + tid; p < P; p += stride) {
    int lb = lab[p]; if (lb < 0) lb = 0; if (lb > NSEGF) lb = NSEGF;
    const int o = lb * RPS;
    unsafeAtomicAdd(&bins[o + 8], 1.f);
    for (int c = 0; c < Cc; ++c)
      unsafeAtomicAdd(&bins[o + c], pred[(size_t)c * P + p]);
  }
  __syncthreads();
  const int grp = blockIdx.x & (NGRP - 1);
  for (int i = tid; i < NROWS; i += BLK) {
    const float v = bins[RPS + i];   // segments 1..32 -> rows (k-1)*RPS + c
    if (v != 0.f) unsafeAtomicAdd(&ws[i * NGRP + grp], v);
  }
}

__global__ __launch_bounds__(256)
void finish_kernel(const float* __restrict__ ws,
                   const int*   __restrict__ nkp,
                   float*       __restrict__ out,
                   int C) {
  __shared__ float sfin[NROWS];
  __shared__ float sA[NSEGF + 1];
  __shared__ float wsum[4];
  int K = *nkp; if (K > NSEGF) K = NSEGF;
  const int tid = threadIdx.x;
  const int Cc = C < 8 ? C : 8;

  // Row v's 32 grouped partials are contiguous (128B) -> per-thread sweep.
  for (int v = tid; v < NROWS; v += 256) {
    const float* r = ws + (size_t)v * NGRP;
    float s = 0.f;
#pragma unroll
    for (int b = 0; b < NGRP; ++b) s += r[b];
    sfin[v] = s;
  }
  __syncthreads();
  for (int k = 1 + tid; k <= K; k += 256) {
    float s2 = 0.f;
    for (int c = 0; c < Cc; ++c) {
      const float v = sfin[(k - 1) * RPS + c];
      s2 = fmaf(v, v, s2);
    }
    sA[k] = sfin[(k - 1) * RPS + 8] * s2;
  }
  __syncthreads();

  // All-lane pair loop (R5 lesson: never serialize transcendentals per lane).
  const int npairs = K * (K - 1) / 2;
  float accv = 0.f;
  for (int idx = tid; idx < npairs; idx += 256) {
    int i = 1, rem = idx;
    while (rem >= K - i) { rem -= K - i; ++i; }
    const int j = i + 1 + rem;
    const float ps = sA[i] + sA[j];
    const float d  = fmaxf(3.0f - sqrtf(ps), 0.f);
    accv += logf(fmaf(d, d, 1.f));
  }
  accv = wave_sum64(accv);
  if ((tid & 63) == 63) wsum[tid >> 6] = accv;
  __syncthreads();
  if (tid == 0)
    out[0] = (wsum[0] + wsum[1] + wsum[2] + wsum[3]) * (float)(K - 1) / (float)K;
}

extern "C" void kernel_launch(void* const* d_in, const int* in_sizes, int n_in,
                              void* d_out, int out_size, void* d_ws, size_t ws_size,
                              hipStream_t stream) {
  const float* pred = (const float*)d_in[0];
  const int*   lab  = (const int*)d_in[2];
  const int*   nkp  = (const int*)d_in[3];
  float*       out  = (float*)d_out;
  float*       ws   = (float*)d_ws;

  const int P = in_sizes[2];        // H*W
  const int C = in_sizes[0] / P;    // channels

  // Zero the 36KB accumulation grid (atomically accumulated each call).
  hipMemsetAsync(d_ws, 0, (size_t)NROWS * NGRP * sizeof(float), stream);

  const size_t need = (size_t)NROWS * NGRP * sizeof(float);
  const int spt = (P / TPX) / NWAVES;
  const bool fast = (C == 8) && (P % (TPX * NWAVES)) == 0 && spt >= 2 &&
                    ws_size >= need;

  if (fast) {
    seg_mfma<<<NBLK, BLK, 0, stream>>>(pred, lab, ws, P);
  } else {
    seg_gen<<<NBLK, BLK, 0, stream>>>(pred, lab, ws, P, C);
  }
  finish_kernel<<<1, 256, 0, stream>>>(ws, nkp, out, C);
}

// Round 22
// 41.485 us; speedup vs baseline: 1.3937x; 1.3937x over previous
//
#include <hip/hip_runtime.h>
#include <hip/hip_bf16.h>
#include <math.h>

// DiscriminationLoss via MFMA (R22 = exact revert to R14, the 41.6us best):
//   S[k,c] = sum_{p: label[p]=k} pred[c,p],  N[k] = |{p: label[p]=k}|, k=1..32
//   A[k]   = N[k] * sum_c S[k,c]^2
//   L      = sum_{i<j} log(max(3 - sqrt(A_i + A_j), 0)^2 + 1);  out = L*(K-1)/K
//
// Final structure after 21 rounds:
//   - seg_mfma: one-hot MFMA segmented sum (dual 16x16x32 bf16), per-wave
//     private 128-px tiles double-buffered in LDS via global_load_lds DMA,
//     counted vmcnt(5) steady-state (never 0), XOR-swizzle byte^((c&7)<<4)
//     on BOTH DMA-source and ds_read (rule #21), XCD-bijective block swizzle,
//     4 blocks/CU. Plain-store per-block slabs.
//   - reduce1: 32 blocks, coalesced slab reads, transposed [row][block] out.
//   - finish: 256 threads, coalesced row reads, all-lane parallel pair loop.
// Falsification ledger (seg plateau ~41.6-41.9us): pipeline depth (R15),
// occupancy 8/16/20w (R12/R15/R20), LDS-read traffic (R16), block-sharing
// (R17), sweep order (R18), granule up (R19), granule down+parallelism (R20),
// tail atomics fenced/fence-free (R11/R21 -- both regress). Practical rate
// for this 9-stream strided gather: ~4.4 TB/s vs 6.3-7.0 unit-stride copy.

typedef __attribute__((ext_vector_type(8))) short short8;
typedef __attribute__((ext_vector_type(4))) float f32x4;

constexpr int NSEGF = 32;            // segments 1..32 (label 0 = background)
constexpr int RPS   = 9;             // 8 channels + count
constexpr int NROWS = NSEGF * RPS;   // 288
constexpr int BLK   = 256;
constexpr int WPB   = 4;
constexpr int NBLK  = 1024;          // 4 blocks/CU co-resident
constexpr int NWAVES= NBLK * WPB;    // 4096 waves
constexpr int TPX   = 128;           // pixels per tile (per wave per buffer)
constexpr int L1BLK = 32;            // level-1 reduce blocks
constexpr int SLABS = NBLK / L1BLK;  // 32 slabs per reduce block
constexpr int L1BASE   = 1024;       // ws float offset: L1 partials [row][block]
constexpr int PARTBASE = 16384;      // ws float offset: per-block slabs [block][row]

#define SCHED_FENCE asm volatile("" ::: "memory")
#define WAITVM(n)   asm volatile("s_waitcnt vmcnt(" #n ")" ::: "memory")

typedef __attribute__((address_space(1))) void A1v;
typedef __attribute__((address_space(3))) void A3v;

__device__ __forceinline__ void gload16(const void* g, void* l) {
  // 16B/lane direct global->LDS DMA; LDS dest = uniform base + lane*16.
  __builtin_amdgcn_global_load_lds((const A1v*)g, (A3v*)l, 16, 0, 0);
}

__device__ __forceinline__ short f2bf(float f) {
  return (short)__bfloat16_as_ushort(__float2bfloat16(f));
}

__device__ __forceinline__ float wave_sum64(float x) {
  int t;
  t = __builtin_amdgcn_update_dpp(0, __float_as_int(x), 0x111, 0xf, 0xf, true); x += __int_as_float(t);
  t = __builtin_amdgcn_update_dpp(0, __float_as_int(x), 0x112, 0xf, 0xf, true); x += __int_as_float(t);
  t = __builtin_amdgcn_update_dpp(0, __float_as_int(x), 0x114, 0xf, 0xf, true); x += __int_as_float(t);
  t = __builtin_amdgcn_update_dpp(0, __float_as_int(x), 0x118, 0xf, 0xf, true); x += __int_as_float(t);
  t = __builtin_amdgcn_update_dpp(0, __float_as_int(x), 0x142, 0xf, 0xf, true); x += __int_as_float(t);
  t = __builtin_amdgcn_update_dpp(0, __float_as_int(x), 0x143, 0xf, 0xf, true); x += __int_as_float(t);
  return x;  // lane 63 holds the sum
}

// Stage one 128-px tile: 4 pred DMA (each covers 2 channel rows of 512B)
// + 1 label DMA (32 lanes). Global source pre-swizzled byte^((c&7)<<4).
__device__ __forceinline__ void stage_tile(const float* __restrict__ pred,
                                           const int*   __restrict__ lab,
                                           float* predbuf, int* labbuf,
                                           size_t px0, int lane, size_t P) {
#pragma unroll
  for (int i = 0; i < 4; ++i) {
    const int c   = 2 * i + (lane >> 5);
    const int swb = (((lane & 31) * 16) ^ ((c & 7) << 4));  // byte within 512B row
    gload16(pred + (size_t)c * P + px0 + (swb >> 2), predbuf + i * 256);
  }
  if (lane < 32) gload16(lab + px0 + lane * 4, labbuf);
}

// Compute one tile (4 steps x 2 MFMA) from this wave's LDS buffer.
__device__ __forceinline__ void compute_tile(const float* __restrict__ pbuf,
                                             const int*   __restrict__ lbuf,
                                             int colq, int quad, int ms0, int ms1,
                                             short8 Bconst,
                                             f32x4& acc0, f32x4& acc1) {
  const short ONE = (short)0x3F80;
  const int  c    = colq & 7;            // lanes 8..15 alias c of colq-8 (broadcast)
  const bool isch = (colq < 8);
  const char* prow = (const char*)(pbuf + c * TPX);
  const int*  lb   = lbuf + quad * 8;
#pragma unroll
  for (int s = 0; s < 4; ++s) {
    const int4 la = *(const int4*)(lb + s * 32);
    const int4 lc = *(const int4*)(lb + s * 32 + 4);
    const int  b0 = (s * 128 + quad * 32) ^ ((c & 7) << 4);   // swizzled byte
    const float4 x = *(const float4*)(prow + b0);
    const float4 y = *(const float4*)(prow + (b0 ^ 16));
    short8 A0, A1, B;
    A0[0] = (la.x == ms0) ? ONE : (short)0;
    A0[1] = (la.y == ms0) ? ONE : (short)0;
    A0[2] = (la.z == ms0) ? ONE : (short)0;
    A0[3] = (la.w == ms0) ? ONE : (short)0;
    A0[4] = (lc.x == ms0) ? ONE : (short)0;
    A0[5] = (lc.y == ms0) ? ONE : (short)0;
    A0[6] = (lc.z == ms0) ? ONE : (short)0;
    A0[7] = (lc.w == ms0) ? ONE : (short)0;
    A1[0] = (la.x == ms1) ? ONE : (short)0;
    A1[1] = (la.y == ms1) ? ONE : (short)0;
    A1[2] = (la.z == ms1) ? ONE : (short)0;
    A1[3] = (la.w == ms1) ? ONE : (short)0;
    A1[4] = (lc.x == ms1) ? ONE : (short)0;
    A1[5] = (lc.y == ms1) ? ONE : (short)0;
    A1[6] = (lc.z == ms1) ? ONE : (short)0;
    A1[7] = (lc.w == ms1) ? ONE : (short)0;
    if (isch) {
      B[0] = f2bf(x.x); B[1] = f2bf(x.y); B[2] = f2bf(x.z); B[3] = f2bf(x.w);
      B[4] = f2bf(y.x); B[5] = f2bf(y.y); B[6] = f2bf(y.z); B[7] = f2bf(y.w);
    } else {
      B = Bconst;
    }
    acc0 = __builtin_amdgcn_mfma_f32_16x16x32_bf16(A0, B, acc0, 0, 0, 0);
    acc1 = __builtin_amdgcn_mfma_f32_16x16x32_bf16(A1, B, acc1, 0, 0, 0);
  }
}

__global__ __launch_bounds__(BLK, 4)
void seg_mfma(const float* __restrict__ pred,
              const int*   __restrict__ lab,
              float*       __restrict__ ws,
              int P) {
  __shared__ __align__(16) float predL[WPB][2][8 * TPX];  // 32 KB (red overlaid)
  __shared__ __align__(16) int   labL[WPB][2][TPX];       // 4 KB

  const int tid  = threadIdx.x;
  const int wid  = tid >> 6;
  const int lane = tid & 63;
  const int colq = lane & 15;   // D col: 0..7 channel, 8 count, 9..15 unused
  const int quad = lane >> 4;   // k-group (8 px each)
  const int ms0  = colq + 1;    // acc0: segments 1..16
  const int ms1  = colq + 17;   // acc1: segments 17..32

  // XCD-bijective block swizzle (1024 % 8 == 0).
  const int bs = (blockIdx.x & 7) * (NBLK / 8) + (blockIdx.x >> 3);
  const int gw = bs * WPB + wid;

  const int spt = (P / TPX) / NWAVES;       // tiles per wave (guarded >= 2)
  const size_t px00 = (size_t)gw * spt * TPX;

  f32x4 acc0 = {0.f, 0.f, 0.f, 0.f};
  f32x4 acc1 = {0.f, 0.f, 0.f, 0.f};

  short8 Bconst;   // col 8 -> bf16 1.0 (counts); cols 9..15 -> 0
  {
    const short v = (colq == 8) ? (short)0x3F80 : (short)0;
#pragma unroll
    for (int i = 0; i < 8; ++i) Bconst[i] = v;
  }

  float* pb0 = &predL[wid][0][0];
  float* pb1 = &predL[wid][1][0];
  int*   lb0 = &labL[wid][0][0];
  int*   lb1 = &labL[wid][1][0];

  // Prologue: stage tiles 0 and 1 (10 DMAs in flight).
  stage_tile(pred, lab, pb0, lb0, px00, lane, (size_t)P);
  stage_tile(pred, lab, pb1, lb1, px00 + TPX, lane, (size_t)P);

  for (int t = 0; t < spt; ++t) {
    // Steady: WAITVM(5) retires tile t's 5 DMAs, leaves tile t+1 in flight.
    if (t < spt - 1) { WAITVM(5); } else { WAITVM(0); }
    const float* pb = (t & 1) ? pb1 : pb0;
    const int*   lb = (t & 1) ? lb1 : lb0;
    compute_tile(pb, lb, colq, quad, ms0, ms1, Bconst, acc0, acc1);
    SCHED_FENCE;   // pin ds_read issue before re-staging this buffer
    if (t + 2 < spt) {
      stage_tile(pred, lab, (t & 1) ? pb1 : pb0, (t & 1) ? lb1 : lb0,
                 px00 + (size_t)(t + 2) * TPX, lane, (size_t)P);
    }
  }

  // Per-wave partials overlaid on this wave's OWN predL (loop done; buffers
  // are wave-private). D layout (m89/m91-verified): col=lane&15,
  // row=(lane>>4)*4+reg. acc0 row r -> seg r+1; acc1 row r -> seg r+17.
  float* redw = &predL[wid][0][0];
  SCHED_FENCE;
  if (colq < RPS) {
#pragma unroll
    for (int r = 0; r < 4; ++r)
      redw[(quad * 4 + r) * RPS + colq] = acc0[r];
#pragma unroll
    for (int r = 0; r < 4; ++r)
      redw[(16 + quad * 4 + r) * RPS + colq] = acc1[r];
  }
  __syncthreads();
  for (int v = tid; v < NROWS; v += BLK) {
    float s = 0.f;
#pragma unroll
    for (int w = 0; w < WPB; ++w) s += predL[w][0][v];
    ws[PARTBASE + (size_t)blockIdx.x * NROWS + v] = s;   // plain-store slab
  }
}

// Level-1: block b sums SLABS contiguous slabs (coalesced reads); writes
// TRANSPOSED [row][block] so finish reads 128B-contiguous rows.
__global__ __launch_bounds__(256)
void reduce1(float* __restrict__ ws) {
  const int b = blockIdx.x;
  for (int v = threadIdx.x; v < NROWS; v += 256) {
    float s = 0.f;
#pragma unroll 4
    for (int i = 0; i < SLABS; ++i)
      s += ws[PARTBASE + (size_t)(b * SLABS + i) * NROWS + v];
    ws[L1BASE + (size_t)v * L1BLK + b] = s;
  }
}

// Fallback (C != 8 or bad divisibility): LDS-atomic bins, plain-store slabs.
__global__ __launch_bounds__(BLK)
void seg_gen(const float* __restrict__ pred,
             const int*   __restrict__ lab,
             float*       __restrict__ ws,
             int P, int C) {
  __shared__ float bins[(NSEGF + 1) * RPS];
  const int tid = threadIdx.x;
  for (int i = tid; i < (NSEGF + 1) * RPS; i += BLK) bins[i] = 0.f;
  __syncthreads();
  const int stride = gridDim.x * BLK;
  const int Cc = C < 8 ? C : 8;
  for (int p = blockIdx.x * BLK + tid; p < P; p += stride) {
    int lb = lab[p]; if (lb < 0) lb = 0; if (lb > NSEGF) lb = NSEGF;
    const int o = lb * RPS;
    unsafeAtomicAdd(&bins[o + 8], 1.f);
    for (int c = 0; c < Cc; ++c)
      unsafeAtomicAdd(&bins[o + c], pred[(size_t)c * P + p]);
  }
  __syncthreads();
  for (int i = tid; i < NROWS; i += BLK)
    ws[PARTBASE + (size_t)blockIdx.x * NROWS + i] = bins[RPS + i];
}

__global__ __launch_bounds__(256)
void finish_kernel(const float* __restrict__ ws,
                   const int*   __restrict__ nkp,
                   float*       __restrict__ out,
                   int C) {
  __shared__ float sfin[NROWS];
  __shared__ float sA[NSEGF + 1];
  __shared__ float wsum[4];
  int K = *nkp; if (K > NSEGF) K = NSEGF;
  const int tid = threadIdx.x;
  const int Cc = C < 8 ? C : 8;

  // Level-2 reduce: row v's 32 partials are contiguous (128B) -> coalesced.
  for (int v = tid; v < NROWS; v += 256) {
    const float* r = ws + L1BASE + (size_t)v * L1BLK;
    float s = 0.f;
#pragma unroll
    for (int b = 0; b < L1BLK; ++b) s += r[b];
    sfin[v] = s;
  }
  __syncthreads();
  for (int k = 1 + tid; k <= K; k += 256) {
    float s2 = 0.f;
    for (int c = 0; c < Cc; ++c) {
      const float v = sfin[(k - 1) * RPS + c];
      s2 = fmaf(v, v, s2);
    }
    sA[k] = sfin[(k - 1) * RPS + 8] * s2;
  }
  __syncthreads();

  // All-lane pair loop (R5 lesson: never serialize transcendentals per lane).
  const int npairs = K * (K - 1) / 2;
  float accv = 0.f;
  for (int idx = tid; idx < npairs; idx += 256) {
    int i = 1, rem = idx;
    while (rem >= K - i) { rem -= K - i; ++i; }
    const int j = i + 1 + rem;
    const float ps = sA[i] + sA[j];
    const float d  = fmaxf(3.0f - sqrtf(ps), 0.f);
    accv += logf(fmaf(d, d, 1.f));
  }
  accv = wave_sum64(accv);
  if ((tid & 63) == 63) wsum[tid >> 6] = accv;
  __syncthreads();
  if (tid == 0)
    out[0] = (wsum[0] + wsum[1] + wsum[2] + wsum[3]) * (float)(K - 1) / (float)K;
}

extern "C" void kernel_launch(void* const* d_in, const int* in_sizes, int n_in,
                              void* d_out, int out_size, void* d_ws, size_t ws_size,
                              hipStream_t stream) {
  const float* pred = (const float*)d_in[0];
  const int*   lab  = (const int*)d_in[2];
  const int*   nkp  = (const int*)d_in[3];
  float*       out  = (float*)d_out;
  float*       ws   = (float*)d_ws;

  const int P = in_sizes[2];        // H*W
  const int C = in_sizes[0] / P;    // channels

  const size_t need = (size_t)(PARTBASE + (size_t)NBLK * NROWS) * sizeof(float);
  const int spt = (P / TPX) / NWAVES;
  const bool fast = (C == 8) && (P % (TPX * NWAVES)) == 0 && spt >= 2 &&
                    ws_size >= need;

  if (fast) {
    seg_mfma<<<NBLK, BLK, 0, stream>>>(pred, lab, ws, P);
  } else {
    seg_gen<<<NBLK, BLK, 0, stream>>>(pred, lab, ws, P, C);
  }
  reduce1<<<L1BLK, 256, 0, stream>>>(ws);
  finish_kernel<<<1, 256, 0, stream>>>(ws, nkp, out, C);
}